// Round 2
// 1584.964 us; speedup vs baseline: 1.4377x; 1.4377x over previous
//
#include <hip/hip_runtime.h>
#include <hip/hip_bf16.h>

// W8A16 linear: M = B*S = 8192, K = IN = 4096, N = OUT = 16384.
// out[m][n] = (sum_k x[m][k]*w[n][k]) * scales[n] + bias[n]
//
// dtype model: x f32 [M][K] (fp16-promoted), w int32 [N][K], scales f32 [N],
// bias f32 [N], out f32 [M][N].
//
// Round-5: 256x256 / BK=64 / 8-wave / 8-phase template, with the round-4 staging
// race FIXED. Hazard ledger (read-certification barriers):
//   buf.A region ds_reads happen in P1 AND P3 (each wave reads both K-slices of
//   its M-half) -> A overwrite may issue only >= P4 (after end-P3 barrier).
//   buf.B region ds_reads happen in P1 AND P2 -> B overwrite may issue >= P3.
// Stage slots: P1: t+1.A1 | P3: t+2.B0 | P4: t+2.B1 + t+2.A0 | P5: t+2.A1
//            | P7: t+3.B0 | P8: t+3.B1 + t+3.A0.   (P2/P6: none)
// vmcnt ledger (2 loads per STAGE): start-of-iter outstanding 6 = t+1.{B0,B1,A0};
// P1 -> 8; P3 -> 10; P4 -> 14, WAIT vmcnt(6) retires oldest 8 = ALL of t+1;
// P5 -> 8; P7 -> 10; P8 -> 14, WAIT vmcnt(6) retires all of t+2. Never 0 in loop.
#define M_DIM 8192
#define N_DIM 16384
#define K_DIM 4096

typedef __attribute__((ext_vector_type(8))) short          bf16x8; // MFMA A/B frag
typedef __attribute__((ext_vector_type(4))) float          f32x4;
typedef __attribute__((ext_vector_type(4))) int            i32x4;
typedef __attribute__((ext_vector_type(8))) unsigned short u16x8;

__device__ __forceinline__ unsigned short f2bf_rne(float f) {
    unsigned int u = __builtin_bit_cast(unsigned int, f);
    return (unsigned short)((u + 0x7fffu + ((u >> 16) & 1u)) >> 16);
}
// int8-range -> f32 -> bf16 truncation is exact (low mantissa bits are zero).
__device__ __forceinline__ unsigned short i2bf(int v) {
    return (unsigned short)(__builtin_bit_cast(unsigned int, (float)v) >> 16);
}

__device__ __forceinline__ void gload_lds16(const void* g, void* l) {
    __builtin_amdgcn_global_load_lds(
        (const __attribute__((address_space(1))) unsigned int*)g,
        (__attribute__((address_space(3))) unsigned int*)l, 16, 0, 0);
}

// ---------------- converters (PRE path), unchanged ----------------
__global__ __launch_bounds__(256) void convert_x_kernel(const float* __restrict__ xi,
                                                        unsigned short* __restrict__ xo) {
    const int idx = (blockIdx.x * 256 + threadIdx.x) * 8;
    f32x4 a = *(const f32x4*)(xi + idx);
    f32x4 b = *(const f32x4*)(xi + idx + 4);
    u16x8 o;
    o[0] = f2bf_rne(a[0]); o[1] = f2bf_rne(a[1]); o[2] = f2bf_rne(a[2]); o[3] = f2bf_rne(a[3]);
    o[4] = f2bf_rne(b[0]); o[5] = f2bf_rne(b[1]); o[6] = f2bf_rne(b[2]); o[7] = f2bf_rne(b[3]);
    *(u16x8*)(xo + idx) = o;
}

__global__ __launch_bounds__(256) void convert_w_kernel(const int* __restrict__ wi,
                                                        unsigned short* __restrict__ wo) {
    const int idx = (blockIdx.x * 256 + threadIdx.x) * 8;
    i32x4 a = *(const i32x4*)(wi + idx);
    i32x4 b = *(const i32x4*)(wi + idx + 4);
    u16x8 o;
    o[0] = i2bf(a[0]); o[1] = i2bf(a[1]); o[2] = i2bf(a[2]); o[3] = i2bf(a[3]);
    o[4] = i2bf(b[0]); o[5] = i2bf(b[1]); o[6] = i2bf(b[2]); o[7] = i2bf(b[3]);
    *(u16x8*)(wo + idx) = o;
}

// ================= 256x256 / BK=64 / 8-wave / 8-phase GEMM (PRE path) ==========
// LDS map (ushort elements): buf b in {0,1}: base = b*32768; A tile [256][64] at +0,
// B tile [256][64] at +16384 (half h = rows [h*128, h*128+128) at +h*8192, which is
// contiguous row-major overall). Swizzle: 16B-chunk q of row r lives at chunk
// position q ^ (r&7). global_load_lds writes LDS linearly (base + lane*16B), so the
// *global source* column is pre-permuted (both-sides-or-neither) and ds_read applies
// the same XOR.

#define BAR()        __builtin_amdgcn_s_barrier()
#define WAIT_LGKM0() asm volatile("s_waitcnt lgkmcnt(0)" ::: "memory")
#define WAIT_VM6()   asm volatile("s_waitcnt vmcnt(6)" ::: "memory")
#define PRIO1()      __builtin_amdgcn_s_setprio(1)
#define PRIO0()      __builtin_amdgcn_s_setprio(0)

// Stage one 128x64 half-tile (16 KB): 512 threads x 2 x global_load_lds(16B).
#define STAGE(gptr, tile, h, bufidx, matoff)                                          \
    do {                                                                              \
        const int _kt = (tile) & 63;                                                  \
        const unsigned short* _s = (gptr) + (size_t)(h) * 128 * K_DIM + _kt * 64;     \
        unsigned short* _d = &smem[(bufidx) * 32768 + (matoff) + (h) * 8192 + sd];    \
        gload_lds16(_s, _d);                                                          \
        gload_lds16(_s + 8 * K_DIM, _d + 512);                                        \
    } while (0)

#define LOAD_A(bufidx, mh)                                                            \
    do {                                                                              \
        _Pragma("unroll")                                                             \
        for (int ii = 0; ii < 4; ++ii) {                                              \
            const int _b = (bufidx) * 32768 + aRow + ((mh) * 4 + ii) * 1024;          \
            a_[ii][0] = *(const bf16x8*)&smem[_b + k0o];                              \
            a_[ii][1] = *(const bf16x8*)&smem[_b + k1o];                              \
        }                                                                             \
    } while (0)

#define LOAD_B(bufidx, nh, breg)                                                      \
    do {                                                                              \
        _Pragma("unroll")                                                             \
        for (int jj = 0; jj < 2; ++jj) {                                              \
            const int _b = (bufidx) * 32768 + 16384 + bRow + ((nh) * 2 + jj) * 1024;  \
            breg[jj][0] = *(const bf16x8*)&smem[_b + k0o];                            \
            breg[jj][1] = *(const bf16x8*)&smem[_b + k1o];                            \
        }                                                                             \
    } while (0)

#define MMA(breg, mh, nh)                                                             \
    do {                                                                              \
        _Pragma("unroll")                                                             \
        for (int ii = 0; ii < 4; ++ii) {                                              \
            _Pragma("unroll")                                                         \
            for (int jj = 0; jj < 2; ++jj) {                                          \
                acc[(mh)*4+ii][(nh)*2+jj] = __builtin_amdgcn_mfma_f32_16x16x32_bf16(  \
                    a_[ii][0], breg[jj][0], acc[(mh)*4+ii][(nh)*2+jj], 0, 0, 0);      \
                acc[(mh)*4+ii][(nh)*2+jj] = __builtin_amdgcn_mfma_f32_16x16x32_bf16(  \
                    a_[ii][1], breg[jj][1], acc[(mh)*4+ii][(nh)*2+jj], 0, 0, 0);      \
            }                                                                         \
        }                                                                             \
    } while (0)

__global__ __launch_bounds__(512, 2) void gemm256(
    const unsigned short* __restrict__ A,  // bf16 [M][K]
    const unsigned short* __restrict__ W,  // bf16 [N][K]
    const float* __restrict__ scales, const float* __restrict__ bias,
    float* __restrict__ C)
{
    __shared__ __align__(16) unsigned short smem[65536]; // 128 KiB: 2 bufs x (A+B)

    const int tid  = threadIdx.x;
    const int ln   = tid & 63, wv = tid >> 6;       // lane, wave (8 waves)
    const int lm   = ln & 15, quad = ln >> 4;
    const int wm   = wv >> 2, wn = wv & 3;          // 2 (M) x 4 (N) wave grid

    // T1: bijective XCD swizzle (2048 % 8 == 0), then column-panel per XCD.
    const int bid = blockIdx.x;
    const int xcd = bid & 7, j0 = bid >> 3;         // j0 in [0,256)
    const int n0 = (xcd * 8 + (j0 & 7)) * 256;      // 64 n-tiles
    const int m0 = (j0 >> 3) * 256;                 // 32 m-tiles

    // ---- staging constants (per lane) ----
    // LDS chunk c = wv*128 + j*64 + ln holds global 16B-chunk (ln&7)^(ln>>3) of
    // local row wv*16 + j*8 + (ln>>3); row&7 == ln>>3 for all h,j.
    const int colq = ((ln & 7) ^ (ln >> 3)) * 8;    // element col within 64-wide slice
    const int srow = wv * 16 + (ln >> 3);           // local staging row (+h*128, +j*8)
    const unsigned short* gA = A + (size_t)(m0 + srow) * K_DIM + colq;
    const unsigned short* gB = W + (size_t)(n0 + srow) * K_DIM + colq;
    const int sd = (wv * 128 + ln) * 8;             // LDS element dest (+j*512 +region)

    // ---- ds_read constants (per lane) ----
    const int aRow = (wm * 128 + lm) * 64;          // + frag*1024
    const int bRow = (wn * 64 + lm) * 64;
    const int sw  = (lm & 7) << 3;                  // XOR swizzle, element units
    const int k0o = (quad * 8) ^ sw;                // kk=0 fragment offset
    const int k1o = (32 + quad * 8) ^ sw;           // kk=1 fragment offset

    f32x4 acc[8][4] = {};
    bf16x8 a_[4][2], b0_[2][2], b1_[2][2];

    // ---- prologue: tile0 fully + tile1 {A0,B0,B1}; drain to 3 half-tiles ----
    STAGE(gA, 0, 0, 0, 0);        // t0.A0 -> buf0
    STAGE(gB, 0, 0, 0, 16384);    // t0.B0
    STAGE(gB, 0, 1, 0, 16384);    // t0.B1
    STAGE(gA, 0, 1, 0, 0);        // t0.A1
    STAGE(gA, 1, 0, 1, 0);        // t1.A0 -> buf1
    STAGE(gB, 1, 0, 1, 16384);    // t1.B0
    STAGE(gB, 1, 1, 1, 16384);    // t1.B1
    WAIT_VM6();                   // t0 all landed; t1 x3 in flight
    BAR();

    // ---- main loop: 2 K-tiles per iter, 8 phases; vmcnt(6) only at P4/P8 ----
    for (int it = 0; it < 32; ++it) {
        const int t = it * 2;
        // ======== K-tile t (buf0) ========
        // P1: (m0,n0); stage t+1.A1 -> buf1.A.h1 (buf1.A certified prev-P7 barrier)
        LOAD_A(0, 0); LOAD_B(0, 0, b0_);
        STAGE(gA, t + 1, 1, 1, 0);
        BAR(); WAIT_LGKM0(); PRIO1(); MMA(b0_, 0, 0); PRIO0(); BAR();
        // P2: (m0,n1); NO stage (no region is read-certified yet)
        LOAD_B(0, 1, b1_);
        BAR(); WAIT_LGKM0(); PRIO1(); MMA(b1_, 0, 1); PRIO0(); BAR();
        // P3: (m1,n0); stage t+2.B0 (buf0.B certified end-P2)
        LOAD_A(0, 1);
        STAGE(gB, t + 2, 0, 0, 16384);
        BAR(); WAIT_LGKM0(); PRIO1(); MMA(b0_, 1, 0); PRIO0(); BAR();
        // P4: (m1,n1); stage t+2.B1 + t+2.A0 (buf0.A certified end-P3);
        //     counted drain: after the barrier, tile t+1 is resident in buf1
        STAGE(gB, t + 2, 1, 0, 16384);
        STAGE(gA, t + 2, 0, 0, 0);
        BAR(); PRIO1(); MMA(b1_, 1, 1); PRIO0(); WAIT_VM6(); BAR();

        // ======== K-tile t+1 (buf1) ========
        // P5: stage t+2.A1 -> buf0.A.h1 (certified end-P3)
        LOAD_A(1, 0); LOAD_B(1, 0, b0_);
        STAGE(gA, t + 2, 1, 0, 0);
        BAR(); WAIT_LGKM0(); PRIO1(); MMA(b0_, 0, 0); PRIO0(); BAR();
        // P6: NO stage
        LOAD_B(1, 1, b1_);
        BAR(); WAIT_LGKM0(); PRIO1(); MMA(b1_, 0, 1); PRIO0(); BAR();
        // P7: stage t+3.B0 (buf1.B certified end-P6)
        LOAD_A(1, 1);
        STAGE(gB, t + 3, 0, 1, 16384);
        BAR(); WAIT_LGKM0(); PRIO1(); MMA(b0_, 1, 0); PRIO0(); BAR();
        // P8: stage t+3.B1 + t+3.A0 (buf1.A certified end-P7);
        //     counted drain: tile t+2 resident in buf0 for next iteration
        STAGE(gB, t + 3, 1, 1, 16384);
        STAGE(gA, t + 3, 0, 1, 0);
        BAR(); PRIO1(); MMA(b1_, 1, 1); PRIO0(); WAIT_VM6(); BAR();
    }

    // ---- epilogue: C/D layout col = lane&15 (n), row = quad*4 + reg (m) ----
#pragma unroll
    for (int f = 0; f < 8; ++f) {
        const int mb = m0 + wm * 128 + f * 16 + quad * 4;
#pragma unroll
        for (int j = 0; j < 4; ++j) {
            const int n = n0 + wn * 64 + j * 16 + lm;
            const float sc = scales[n];
            const float bv = bias[n];
            float* cp = C + (size_t)mb * N_DIM + n;
#pragma unroll
            for (int r = 0; r < 4; ++r)
                cp[(size_t)r * N_DIM] = acc[f][j][r] * sc + bv;
        }
    }
}

// ---------------- fallback GEMM: fused convert, no workspace (unchanged) -----
__device__ __forceinline__ void tile_origin(int bid, int& m0, int& n0) {
    const int ls = bid & 63, st = bid >> 6;
    m0 = ((st & 7) * 8 + (ls & 7)) * 128;
    n0 = ((st >> 3) * 8 + (ls >> 3)) * 128;
}

__device__ __forceinline__ void epilogue128(const f32x4 acc[4][4], int m0, int n0,
                                            int lm, int quad, int wr, int wc,
                                            const float* __restrict__ scales,
                                            const float* __restrict__ bias,
                                            float* __restrict__ C) {
#pragma unroll
    for (int j = 0; j < 4; ++j) {
        const int n  = n0 + wc * 64 + j * 16 + lm;
        const float sc = scales[n];
        const float bv = bias[n];
#pragma unroll
        for (int i = 0; i < 4; ++i) {
            const int mb = m0 + wr * 64 + i * 16 + quad * 4;
#pragma unroll
            for (int r = 0; r < 4; ++r)
                C[(long)(mb + r) * N_DIM + n] = acc[i][j][r] * sc + bv;
        }
    }
}

__global__ __launch_bounds__(256) void gemm_fused(
    const float* __restrict__ X,
    const int* __restrict__ W,
    const float* __restrict__ scales, const float* __restrict__ bias,
    float* __restrict__ C)
{
    constexpr int BK = 32;
    __shared__ __align__(16) unsigned short As[128 * BK];
    __shared__ __align__(16) unsigned short Bs[128 * BK];

    const int tid = threadIdx.x;
    int m0, n0; tile_origin(blockIdx.x, m0, n0);
    const int lane = tid & 63, lm = lane & 15, quad = lane >> 4;
    const int wr = (tid >> 7) & 1, wc = (tid >> 6) & 1;

    const int rA = tid >> 2, cA = (tid & 3) * 8;
    const float* gA0 = X + (long)(m0 + rA) * K_DIM + cA;
    const float* gA1 = gA0 + (long)64 * K_DIM;
    const int rB = tid >> 1, hB = (tid & 1) * 16;
    const int* gB = W + (long)(n0 + rB) * K_DIM + hB;

    f32x4 acc[4][4] = {};

    for (int k0 = 0; k0 < K_DIM; k0 += BK) {
        f32x4 xa0 = *(const f32x4*)(gA0 + k0), xa1 = *(const f32x4*)(gA0 + k0 + 4);
        f32x4 xb0 = *(const f32x4*)(gA1 + k0), xb1 = *(const f32x4*)(gA1 + k0 + 4);
        i32x4 w0 = *(const i32x4*)(gB + k0),      w1 = *(const i32x4*)(gB + k0 + 4);
        i32x4 w2 = *(const i32x4*)(gB + k0 + 8),  w3 = *(const i32x4*)(gB + k0 + 12);

        __syncthreads();

        u16x8 oa, ob, wb0, wb1;
        oa[0]=f2bf_rne(xa0[0]); oa[1]=f2bf_rne(xa0[1]); oa[2]=f2bf_rne(xa0[2]); oa[3]=f2bf_rne(xa0[3]);
        oa[4]=f2bf_rne(xa1[0]); oa[5]=f2bf_rne(xa1[1]); oa[6]=f2bf_rne(xa1[2]); oa[7]=f2bf_rne(xa1[3]);
        ob[0]=f2bf_rne(xb0[0]); ob[1]=f2bf_rne(xb0[1]); ob[2]=f2bf_rne(xb0[2]); ob[3]=f2bf_rne(xb0[3]);
        ob[4]=f2bf_rne(xb1[0]); ob[5]=f2bf_rne(xb1[1]); ob[6]=f2bf_rne(xb1[2]); ob[7]=f2bf_rne(xb1[3]);
        *(u16x8*)&As[rA * BK + cA]        = oa;
        *(u16x8*)&As[(rA + 64) * BK + cA] = ob;
        wb0[0]=i2bf(w0[0]); wb0[1]=i2bf(w0[1]); wb0[2]=i2bf(w0[2]); wb0[3]=i2bf(w0[3]);
        wb0[4]=i2bf(w1[0]); wb0[5]=i2bf(w1[1]); wb0[6]=i2bf(w1[2]); wb0[7]=i2bf(w1[3]);
        wb1[0]=i2bf(w2[0]); wb1[1]=i2bf(w2[1]); wb1[2]=i2bf(w2[2]); wb1[3]=i2bf(w2[3]);
        wb1[4]=i2bf(w3[0]); wb1[5]=i2bf(w3[1]); wb1[6]=i2bf(w3[2]); wb1[7]=i2bf(w3[3]);
        *(u16x8*)&Bs[rB * BK + hB]     = wb0;
        *(u16x8*)&Bs[rB * BK + hB + 8] = wb1;

        __syncthreads();

        bf16x8 af[4], bf[4];
#pragma unroll
        for (int i = 0; i < 4; ++i)
            af[i] = *(const bf16x8*)&As[(wr * 64 + i * 16 + lm) * BK + quad * 8];
#pragma unroll
        for (int j = 0; j < 4; ++j)
            bf[j] = *(const bf16x8*)&Bs[(wc * 64 + j * 16 + lm) * BK + quad * 8];
#pragma unroll
        for (int i = 0; i < 4; ++i)
#pragma unroll
            for (int j = 0; j < 4; ++j)
                acc[i][j] = __builtin_amdgcn_mfma_f32_16x16x32_bf16(af[i], bf[j], acc[i][j], 0, 0, 0);
    }
    epilogue128(acc, m0, n0, lm, quad, wr, wc, scales, bias, C);
}

extern "C" void kernel_launch(void* const* d_in, const int* in_sizes, int n_in,
                              void* d_out, int out_size, void* d_ws, size_t ws_size,
                              hipStream_t stream) {
    const float* x  = (const float*)d_in[0]; // f32 [B,S,IN] (fp16-promoted)
    const int*   wq = (const int*)d_in[1];   // int32 [OUT,IN]
    const float* sc = (const float*)d_in[2]; // f32 [OUT]
    const float* bi = (const float*)d_in[3]; // f32 [OUT]
    float*       out = (float*)d_out;        // f32 [M][OUT]

    const size_t xbf_bytes = (size_t)M_DIM * K_DIM * 2;
    const size_t wbf_bytes = (size_t)N_DIM * K_DIM * 2;

    if (ws_size >= xbf_bytes + wbf_bytes) {
        unsigned short* xbf = (unsigned short*)d_ws;
        unsigned short* wbf = (unsigned short*)((char*)d_ws + xbf_bytes);
        convert_x_kernel<<<(M_DIM * K_DIM) / 2048, 256, 0, stream>>>(x, xbf);
        convert_w_kernel<<<(N_DIM * K_DIM) / 2048, 256, 0, stream>>>(wq, wbf);
        const int gemm_blocks = (M_DIM / 256) * (N_DIM / 256); // 2048
        gemm256<<<gemm_blocks, 512, 0, stream>>>(xbf, wbf, sc, bi, out);
    } else {
        const int gemm_blocks = (M_DIM / 128) * (N_DIM / 128); // 8192
        gemm_fused<<<gemm_blocks, 256, 0, stream>>>(x, wq, sc, bi, out);
    }
}

// Round 3
// 1461.800 us; speedup vs baseline: 1.5588x; 1.0843x over previous
//
#include <hip/hip_runtime.h>
#include <hip/hip_bf16.h>

// W8A16 linear: M = B*S = 8192, K = IN = 4096, N = OUT = 16384.
// out[m][n] = (sum_k x[m][k]*w[n][k]) * scales[n] + bias[n]
//
// dtype model: x f32 [M][K] (fp16-promoted), w int32 [N][K], scales f32 [N],
// bias f32 [N], out f32 [M][N].
//
// Round-6 (from passing round-5 @ gemm 985us, MfmaUtil 51%):
//  (1) barriers 16 -> 8 per iter: begin-phase barriers removed; all staging
//      hazards are certified by END-of-phase barriers (proof in comments).
//  (2) register-load pipelining: B1 / A1 fragment ds_reads moved to the TAIL of
//      the previous MFMA cluster (sched_barrier(0)-pinned), hiding their latency
//      under MFMA + barrier. Explicit lgkmcnt(0) dropped -- reads are plain
//      loads, hipcc emits fine-grained lgkmcnt(N) (m97-verified).
//  (3) nontemporal C stores: C (512 MB, never re-read) no longer thrashes L2/L3
//      that A/W panels need (FETCH was 810 MB vs 192 MB ideal).
//  (4) converters fused into one grid-stride kernel, nt input loads (gap probe).
// Certification ledger (per K-tile t in buf0; barriers E1..E4 = end-of-phase):
//   b0_ reads (P1 head) complete before P1 MMA; b1_ (P1 tail) before P2 MMA
//     -> buf0.B fully read before E2  -> stage t+2.B0 @P3, t+2.B1 @P4 legal.
//   A0 reads (P1 head) before P1 MMA; A1 (P2 tail) before P3 MMA
//     -> buf0.A fully read before E3  -> stage t+2.A0 @P4, t+2.A1 @P5 legal.
//   stage t+1.A1 @P1 targets buf1.A: certified by prev-iter E(P7).
// vmcnt ledger (2 loads/STAGE): entry 6 = t+1.{B0,B1,A0}; P1 +2 -> 8;
//   P3 +2 -> 10; P4 +4 -> 14; WAIT vmcnt(6) retires oldest 8 = ALL of t+1.
//   Mirror for t+1/buf1. Never drained to 0 in the loop.
#define M_DIM 8192
#define N_DIM 16384
#define K_DIM 4096

typedef __attribute__((ext_vector_type(8))) short          bf16x8; // MFMA A/B frag
typedef __attribute__((ext_vector_type(4))) float          f32x4;
typedef __attribute__((ext_vector_type(4))) int            i32x4;
typedef __attribute__((ext_vector_type(8))) unsigned short u16x8;

__device__ __forceinline__ unsigned short f2bf_rne(float f) {
    unsigned int u = __builtin_bit_cast(unsigned int, f);
    return (unsigned short)((u + 0x7fffu + ((u >> 16) & 1u)) >> 16);
}
// int8-range -> f32 -> bf16 truncation is exact (low mantissa bits are zero).
__device__ __forceinline__ unsigned short i2bf(int v) {
    return (unsigned short)(__builtin_bit_cast(unsigned int, (float)v) >> 16);
}

__device__ __forceinline__ void gload_lds16(const void* g, void* l) {
    __builtin_amdgcn_global_load_lds(
        (const __attribute__((address_space(1))) unsigned int*)g,
        (__attribute__((address_space(3))) unsigned int*)l, 16, 0, 0);
}

// ---------------- fused converter (PRE path) ----------------
__global__ __launch_bounds__(256) void convert_both(
    const float* __restrict__ xi, const int* __restrict__ wi,
    unsigned short* __restrict__ xo, unsigned short* __restrict__ wo)
{
    const int stride = gridDim.x * 256;
    const int tid0 = blockIdx.x * 256 + threadIdx.x;
    constexpr int XV = M_DIM * K_DIM / 8;  // 4,194,304 vec8 tasks
    constexpr int WV = N_DIM * K_DIM / 8;  // 8,388,608 vec8 tasks
    for (int v = tid0; v < XV; v += stride) {
        const f32x4* p = (const f32x4*)(xi + (size_t)v * 8);
        f32x4 a = __builtin_nontemporal_load(p);
        f32x4 b = __builtin_nontemporal_load(p + 1);
        u16x8 o;
        o[0] = f2bf_rne(a[0]); o[1] = f2bf_rne(a[1]); o[2] = f2bf_rne(a[2]); o[3] = f2bf_rne(a[3]);
        o[4] = f2bf_rne(b[0]); o[5] = f2bf_rne(b[1]); o[6] = f2bf_rne(b[2]); o[7] = f2bf_rne(b[3]);
        *(u16x8*)(xo + (size_t)v * 8) = o;   // normal store: GEMM reads it next
    }
    for (int v = tid0; v < WV; v += stride) {
        const i32x4* p = (const i32x4*)(wi + (size_t)v * 8);
        i32x4 a = __builtin_nontemporal_load(p);
        i32x4 b = __builtin_nontemporal_load(p + 1);
        u16x8 o;
        o[0] = i2bf(a[0]); o[1] = i2bf(a[1]); o[2] = i2bf(a[2]); o[3] = i2bf(a[3]);
        o[4] = i2bf(b[0]); o[5] = i2bf(b[1]); o[6] = i2bf(b[2]); o[7] = i2bf(b[3]);
        *(u16x8*)(wo + (size_t)v * 8) = o;
    }
}

// ================= 256x256 / BK=64 / 8-wave / 8-phase GEMM (PRE path) ==========
// LDS map (ushort elements): buf b in {0,1}: base = b*32768; A tile [256][64] at +0,
// B tile [256][64] at +16384 (half h at +h*8192). Swizzle: 16B-chunk q of row r
// lives at chunk position q ^ (r&7); global_load_lds writes linearly, so the
// GLOBAL source column is pre-permuted and ds_read applies the same XOR.

#define BAR()       __builtin_amdgcn_s_barrier()
#define WAIT_VM6()  asm volatile("s_waitcnt vmcnt(6)" ::: "memory")
#define PRIO1()     __builtin_amdgcn_s_setprio(1)
#define PRIO0()     __builtin_amdgcn_s_setprio(0)
#define SCHED0()    __builtin_amdgcn_sched_barrier(0)

// Stage one 128x64 half-tile (16 KB): 512 threads x 2 x global_load_lds(16B).
#define STAGE(gptr, tile, h, bufidx, matoff)                                          \
    do {                                                                              \
        const int _kt = (tile) & 63;                                                  \
        const unsigned short* _s = (gptr) + (size_t)(h) * 128 * K_DIM + _kt * 64;     \
        unsigned short* _d = &smem[(bufidx) * 32768 + (matoff) + (h) * 8192 + sd];    \
        gload_lds16(_s, _d);                                                          \
        gload_lds16(_s + 8 * K_DIM, _d + 512);                                        \
    } while (0)

#define LOAD_A(bufidx, mh)                                                            \
    do {                                                                              \
        _Pragma("unroll")                                                             \
        for (int ii = 0; ii < 4; ++ii) {                                              \
            const int _b = (bufidx) * 32768 + aRow + ((mh) * 4 + ii) * 1024;          \
            a_[ii][0] = *(const bf16x8*)&smem[_b + k0o];                              \
            a_[ii][1] = *(const bf16x8*)&smem[_b + k1o];                              \
        }                                                                             \
    } while (0)

#define LOAD_B(bufidx, nh, breg)                                                      \
    do {                                                                              \
        _Pragma("unroll")                                                             \
        for (int jj = 0; jj < 2; ++jj) {                                              \
            const int _b = (bufidx) * 32768 + 16384 + bRow + ((nh) * 2 + jj) * 1024;  \
            breg[jj][0] = *(const bf16x8*)&smem[_b + k0o];                            \
            breg[jj][1] = *(const bf16x8*)&smem[_b + k1o];                            \
        }                                                                             \
    } while (0)

#define MMA(breg, mh, nh)                                                             \
    do {                                                                              \
        _Pragma("unroll")                                                             \
        for (int ii = 0; ii < 4; ++ii) {                                              \
            _Pragma("unroll")                                                         \
            for (int jj = 0; jj < 2; ++jj) {                                          \
                acc[(mh)*4+ii][(nh)*2+jj] = __builtin_amdgcn_mfma_f32_16x16x32_bf16(  \
                    a_[ii][0], breg[jj][0], acc[(mh)*4+ii][(nh)*2+jj], 0, 0, 0);      \
                acc[(mh)*4+ii][(nh)*2+jj] = __builtin_amdgcn_mfma_f32_16x16x32_bf16(  \
                    a_[ii][1], breg[jj][1], acc[(mh)*4+ii][(nh)*2+jj], 0, 0, 0);      \
            }                                                                         \
        }                                                                             \
    } while (0)

__global__ __launch_bounds__(512, 2) void gemm256(
    const unsigned short* __restrict__ A,  // bf16 [M][K]
    const unsigned short* __restrict__ W,  // bf16 [N][K]
    const float* __restrict__ scales, const float* __restrict__ bias,
    float* __restrict__ C)
{
    __shared__ __align__(16) unsigned short smem[65536]; // 128 KiB: 2 bufs x (A+B)

    const int tid  = threadIdx.x;
    const int ln   = tid & 63, wv = tid >> 6;       // lane, wave (8 waves)
    const int lm   = ln & 15, quad = ln >> 4;
    const int wm   = wv >> 2, wn = wv & 3;          // 2 (M) x 4 (N) wave grid

    // T1: bijective XCD swizzle (2048 % 8 == 0), then column-panel per XCD.
    const int bid = blockIdx.x;
    const int xcd = bid & 7, j0 = bid >> 3;         // j0 in [0,256)
    const int n0 = (xcd * 8 + (j0 & 7)) * 256;      // 64 n-tiles
    const int m0 = (j0 >> 3) * 256;                 // 32 m-tiles

    // ---- staging constants (per lane) ----
    const int colq = ((ln & 7) ^ (ln >> 3)) * 8;    // pre-swizzled source column
    const int srow = wv * 16 + (ln >> 3);           // local staging row (+h*128, +j*8)
    const unsigned short* gA = A + (size_t)(m0 + srow) * K_DIM + colq;
    const unsigned short* gB = W + (size_t)(n0 + srow) * K_DIM + colq;
    const int sd = (wv * 128 + ln) * 8;             // LDS element dest (+j*512 +region)

    // ---- ds_read constants (per lane) ----
    const int aRow = (wm * 128 + lm) * 64;          // + frag*1024
    const int bRow = (wn * 64 + lm) * 64;
    const int sw  = (lm & 7) << 3;                  // XOR swizzle, element units
    const int k0o = (quad * 8) ^ sw;                // kk=0 fragment offset
    const int k1o = (32 + quad * 8) ^ sw;           // kk=1 fragment offset

    f32x4 acc[8][4] = {};
    bf16x8 a_[4][2], b0_[2][2], b1_[2][2];

    // ---- prologue: tile0 fully + tile1 {A0,B0,B1}; drain to 3 half-tiles ----
    STAGE(gA, 0, 0, 0, 0);        // t0.A0 -> buf0
    STAGE(gB, 0, 0, 0, 16384);    // t0.B0
    STAGE(gB, 0, 1, 0, 16384);    // t0.B1
    STAGE(gA, 0, 1, 0, 0);        // t0.A1
    STAGE(gA, 1, 0, 1, 0);        // t1.A0 -> buf1
    STAGE(gB, 1, 0, 1, 16384);    // t1.B0
    STAGE(gB, 1, 1, 1, 16384);    // t1.B1
    WAIT_VM6();                   // t0 all landed; t1 x3 in flight
    BAR();

    // ---- main loop: 2 K-tiles per iter, 8 MFMA phases, 8 barriers ----
    for (int it = 0; it < 32; ++it) {
        const int t = it * 2;
        // ======== K-tile t (buf0) ========
        // P1: (m0,n0); stage t+1.A1 -> buf1.A.h1 (certified prev E(P7));
        //     tail: b1_ reads (hidden under MFMA + barrier)
        LOAD_A(0, 0); LOAD_B(0, 0, b0_);
        STAGE(gA, t + 1, 1, 1, 0);
        PRIO1(); MMA(b0_, 0, 0); PRIO0();
        SCHED0(); LOAD_B(0, 1, b1_);
        BAR();                                     // E1
        // P2: (m0,n1); tail: a_ <- A1 reads
        PRIO1(); MMA(b1_, 0, 1); PRIO0();
        SCHED0(); LOAD_A(0, 1);
        BAR();                                     // E2: buf0.B fully read
        // P3: (m1,n0); stage t+2.B0
        STAGE(gB, t + 2, 0, 0, 16384);
        PRIO1(); MMA(b0_, 1, 0); PRIO0();
        BAR();                                     // E3: buf0.A fully read
        // P4: (m1,n1); stage t+2.B1 + t+2.A0; counted drain -> t+1 resident
        STAGE(gB, t + 2, 1, 0, 16384);
        STAGE(gA, t + 2, 0, 0, 0);
        PRIO1(); MMA(b1_, 1, 1); PRIO0();
        WAIT_VM6();
        BAR();                                     // E4: announce t+1 in buf1

        // ======== K-tile t+1 (buf1) ======== (mirror)
        // P5: stage t+2.A1 -> buf0.A.h1 (certified E3)
        LOAD_A(1, 0); LOAD_B(1, 0, b0_);
        STAGE(gA, t + 2, 1, 0, 0);
        PRIO1(); MMA(b0_, 0, 0); PRIO0();
        SCHED0(); LOAD_B(1, 1, b1_);
        BAR();                                     // E5
        // P6
        PRIO1(); MMA(b1_, 0, 1); PRIO0();
        SCHED0(); LOAD_A(1, 1);
        BAR();                                     // E6: buf1.B fully read
        // P7: stage t+3.B0
        STAGE(gB, t + 3, 0, 1, 16384);
        PRIO1(); MMA(b0_, 1, 0); PRIO0();
        BAR();                                     // E7: buf1.A fully read
        // P8: stage t+3.B1 + t+3.A0; counted drain -> t+2 resident
        STAGE(gB, t + 3, 1, 1, 16384);
        STAGE(gA, t + 3, 0, 1, 0);
        PRIO1(); MMA(b1_, 1, 1); PRIO0();
        WAIT_VM6();
        BAR();                                     // E8: announce t+2 in buf0
    }

    // ---- epilogue: C/D layout col = lane&15 (n), row = quad*4 + reg (m) ----
    // nontemporal: C is write-once, never re-read -> keep L2/L3 for A/W panels.
#pragma unroll
    for (int f = 0; f < 8; ++f) {
        const int mb = m0 + wm * 128 + f * 16 + quad * 4;
#pragma unroll
        for (int j = 0; j < 4; ++j) {
            const int n = n0 + wn * 64 + j * 16 + lm;
            const float sc = scales[n];
            const float bv = bias[n];
            float* cp = C + (size_t)mb * N_DIM + n;
#pragma unroll
            for (int r = 0; r < 4; ++r)
                __builtin_nontemporal_store(acc[f][j][r] * sc + bv, cp + (size_t)r * N_DIM);
        }
    }
}

// ---------------- fallback GEMM: fused convert, no workspace (unchanged) -----
__device__ __forceinline__ void tile_origin(int bid, int& m0, int& n0) {
    const int ls = bid & 63, st = bid >> 6;
    m0 = ((st & 7) * 8 + (ls & 7)) * 128;
    n0 = ((st >> 3) * 8 + (ls >> 3)) * 128;
}

__device__ __forceinline__ void epilogue128(const f32x4 acc[4][4], int m0, int n0,
                                            int lm, int quad, int wr, int wc,
                                            const float* __restrict__ scales,
                                            const float* __restrict__ bias,
                                            float* __restrict__ C) {
#pragma unroll
    for (int j = 0; j < 4; ++j) {
        const int n  = n0 + wc * 64 + j * 16 + lm;
        const float sc = scales[n];
        const float bv = bias[n];
#pragma unroll
        for (int i = 0; i < 4; ++i) {
            const int mb = m0 + wr * 64 + i * 16 + quad * 4;
#pragma unroll
            for (int r = 0; r < 4; ++r)
                C[(long)(mb + r) * N_DIM + n] = acc[i][j][r] * sc + bv;
        }
    }
}

__global__ __launch_bounds__(256) void gemm_fused(
    const float* __restrict__ X,
    const int* __restrict__ W,
    const float* __restrict__ scales, const float* __restrict__ bias,
    float* __restrict__ C)
{
    constexpr int BK = 32;
    __shared__ __align__(16) unsigned short As[128 * BK];
    __shared__ __align__(16) unsigned short Bs[128 * BK];

    const int tid = threadIdx.x;
    int m0, n0; tile_origin(blockIdx.x, m0, n0);
    const int lane = tid & 63, lm = lane & 15, quad = lane >> 4;
    const int wr = (tid >> 7) & 1, wc = (tid >> 6) & 1;

    const int rA = tid >> 2, cA = (tid & 3) * 8;
    const float* gA0 = X + (long)(m0 + rA) * K_DIM + cA;
    const float* gA1 = gA0 + (long)64 * K_DIM;
    const int rB = tid >> 1, hB = (tid & 1) * 16;
    const int* gB = W + (long)(n0 + rB) * K_DIM + hB;

    f32x4 acc[4][4] = {};

    for (int k0 = 0; k0 < K_DIM; k0 += BK) {
        f32x4 xa0 = *(const f32x4*)(gA0 + k0), xa1 = *(const f32x4*)(gA0 + k0 + 4);
        f32x4 xb0 = *(const f32x4*)(gA1 + k0), xb1 = *(const f32x4*)(gA1 + k0 + 4);
        i32x4 w0 = *(const i32x4*)(gB + k0),      w1 = *(const i32x4*)(gB + k0 + 4);
        i32x4 w2 = *(const i32x4*)(gB + k0 + 8),  w3 = *(const i32x4*)(gB + k0 + 12);

        __syncthreads();

        u16x8 oa, ob, wb0, wb1;
        oa[0]=f2bf_rne(xa0[0]); oa[1]=f2bf_rne(xa0[1]); oa[2]=f2bf_rne(xa0[2]); oa[3]=f2bf_rne(xa0[3]);
        oa[4]=f2bf_rne(xa1[0]); oa[5]=f2bf_rne(xa1[1]); oa[6]=f2bf_rne(xa1[2]); oa[7]=f2bf_rne(xa1[3]);
        ob[0]=f2bf_rne(xb0[0]); ob[1]=f2bf_rne(xb0[1]); ob[2]=f2bf_rne(xb0[2]); ob[3]=f2bf_rne(xb0[3]);
        ob[4]=f2bf_rne(xb1[0]); ob[5]=f2bf_rne(xb1[1]); ob[6]=f2bf_rne(xb1[2]); ob[7]=f2bf_rne(xb1[3]);
        *(u16x8*)&As[rA * BK + cA]        = oa;
        *(u16x8*)&As[(rA + 64) * BK + cA] = ob;
        wb0[0]=i2bf(w0[0]); wb0[1]=i2bf(w0[1]); wb0[2]=i2bf(w0[2]); wb0[3]=i2bf(w0[3]);
        wb0[4]=i2bf(w1[0]); wb0[5]=i2bf(w1[1]); wb0[6]=i2bf(w1[2]); wb0[7]=i2bf(w1[3]);
        wb1[0]=i2bf(w2[0]); wb1[1]=i2bf(w2[1]); wb1[2]=i2bf(w2[2]); wb1[3]=i2bf(w2[3]);
        wb1[4]=i2bf(w3[0]); wb1[5]=i2bf(w3[1]); wb1[6]=i2bf(w3[2]); wb1[7]=i2bf(w3[3]);
        *(u16x8*)&Bs[rB * BK + hB]     = wb0;
        *(u16x8*)&Bs[rB * BK + hB + 8] = wb1;

        __syncthreads();

        bf16x8 af[4], bf[4];
#pragma unroll
        for (int i = 0; i < 4; ++i)
            af[i] = *(const bf16x8*)&As[(wr * 64 + i * 16 + lm) * BK + quad * 8];
#pragma unroll
        for (int j = 0; j < 4; ++j)
            bf[j] = *(const bf16x8*)&Bs[(wc * 64 + j * 16 + lm) * BK + quad * 8];
#pragma unroll
        for (int i = 0; i < 4; ++i)
#pragma unroll
            for (int j = 0; j < 4; ++j)
                acc[i][j] = __builtin_amdgcn_mfma_f32_16x16x32_bf16(af[i], bf[j], acc[i][j], 0, 0, 0);
    }
    epilogue128(acc, m0, n0, lm, quad, wr, wc, scales, bias, C);
}

extern "C" void kernel_launch(void* const* d_in, const int* in_sizes, int n_in,
                              void* d_out, int out_size, void* d_ws, size_t ws_size,
                              hipStream_t stream) {
    const float* x  = (const float*)d_in[0]; // f32 [B,S,IN] (fp16-promoted)
    const int*   wq = (const int*)d_in[1];   // int32 [OUT,IN]
    const float* sc = (const float*)d_in[2]; // f32 [OUT]
    const float* bi = (const float*)d_in[3]; // f32 [OUT]
    float*       out = (float*)d_out;        // f32 [M][OUT]

    const size_t xbf_bytes = (size_t)M_DIM * K_DIM * 2;
    const size_t wbf_bytes = (size_t)N_DIM * K_DIM * 2;

    if (ws_size >= xbf_bytes + wbf_bytes) {
        unsigned short* xbf = (unsigned short*)d_ws;
        unsigned short* wbf = (unsigned short*)((char*)d_ws + xbf_bytes);
        convert_both<<<4096, 256, 0, stream>>>(x, wq, xbf, wbf);
        const int gemm_blocks = (M_DIM / 256) * (N_DIM / 256); // 2048
        gemm256<<<gemm_blocks, 512, 0, stream>>>(xbf, wbf, sc, bi, out);
    } else {
        const int gemm_blocks = (M_DIM / 128) * (N_DIM / 128); // 8192
        gemm_fused<<<gemm_blocks, 256, 0, stream>>>(x, wq, sc, bi, out);
    }
}